// Round 1
// baseline (175.547 us; speedup 1.0000x reference)
//
#include <hip/hip_runtime.h>
#include <hip/hip_bf16.h>

#define N_ATOMS 51200
#define N_MOL   512
#define FEAT    384

// Output layout (flat, in reference return order):
//   energy        [512]      @ 0
//   forces        [153600]   @ 512
//   stress        [4608]     @ 154112
//   energy_uncert [512]      @ 158720   (constant 0.6)
//   force_uncert  [153600]   @ 159232   (computed)
//   stress_uncert [4608]     @ 312832   (constant 0.1/16)
#define OUT_FUNC   159232
#define COPY_TOTAL 163840   // 512+153600+4608+512+4608

constexpr int TA  = 64;   // atoms per block
constexpr int BLK = 256;

__global__ __launch_bounds__(BLK) void funcert_kernel(
    const float* __restrict__ nf,
    const float* __restrict__ energy,
    const float* __restrict__ forces,
    const float* __restrict__ stress,
    const float* __restrict__ W1f, const float* __restrict__ b1f,
    const float* __restrict__ W2f, const float* __restrict__ b2f,
    const float* __restrict__ W3f, const float* __restrict__ b3f,
    float* __restrict__ out)
{
    const int t   = threadIdx.x;
    const int gid = blockIdx.x * BLK + t;

    // ---- passthrough / constant outputs: one element per thread ----
    if (gid < COPY_TOTAL) {
        float v; int o = gid;
        if      (gid < 512)    { v = energy[gid]; }
        else if (gid < 154112) { v = forces[gid - 512]; }
        else if (gid < 158720) { v = stress[gid - 154112]; }
        else if (gid < 159232) { v = 0.6f; }                       // energy_uncert
        else                   { v = 0.1f / 16.0f; o = gid + 153600; } // stress_uncert
        out[o] = v;
    }

    // ---- F-head MLP over TA=64 atoms ----
    __shared__ float h1[TA][68];   // 64x64, padded stride 68 (16B-aligned rows, conflict-light)
    __shared__ float h2[TA][17];   // 64x16, padded

    const int abase = blockIdx.x * TA;
    const int tx = t & 15;    // channel group: channels 4*tx .. 4*tx+3
    const int ty = t >> 4;    // atom group:    atoms    4*ty .. 4*ty+3

    // Layer 1: [64 atoms x 256] @ W1f^T -> [64 x 64], register-tiled 4x4
    float acc[4][4];
    #pragma unroll
    for (int a = 0; a < 4; ++a)
        #pragma unroll
        for (int c = 0; c < 4; ++c) acc[a][c] = 0.0f;

    const float* xrow[4];
    #pragma unroll
    for (int a = 0; a < 4; ++a)
        xrow[a] = nf + (size_t)(abase + 4 * ty + a) * FEAT;
    const float* wrow[4];
    #pragma unroll
    for (int c = 0; c < 4; ++c)
        wrow[c] = W1f + (4 * tx + c) * 256;

    #pragma unroll 2
    for (int k = 0; k < 256; k += 4) {
        // concat: k<128 -> col k of node_feats; k>=128 -> col k+128 (last 128 of 384)
        const int col = k + ((k >= 128) ? 128 : 0);
        float4 xa[4], wc[4];
        #pragma unroll
        for (int a = 0; a < 4; ++a)
            xa[a] = *reinterpret_cast<const float4*>(xrow[a] + col);
        #pragma unroll
        for (int c = 0; c < 4; ++c)
            wc[c] = *reinterpret_cast<const float4*>(wrow[c] + k);
        #pragma unroll
        for (int a = 0; a < 4; ++a) {
            #pragma unroll
            for (int c = 0; c < 4; ++c) {
                acc[a][c] = fmaf(xa[a].x, wc[c].x, acc[a][c]);
                acc[a][c] = fmaf(xa[a].y, wc[c].y, acc[a][c]);
                acc[a][c] = fmaf(xa[a].z, wc[c].z, acc[a][c]);
                acc[a][c] = fmaf(xa[a].w, wc[c].w, acc[a][c]);
            }
        }
    }

    #pragma unroll
    for (int a = 0; a < 4; ++a) {
        #pragma unroll
        for (int c = 0; c < 4; ++c) {
            float v = acc[a][c] + b1f[4 * tx + c];
            v = v / (1.0f + __expf(-v));            // silu
            h1[4 * ty + a][4 * tx + c] = v;
        }
    }
    __syncthreads();

    // Layer 2: [64 x 64] @ W2f^T -> [64 x 16]; thread owns 1 atom x 4 ch
    const int a2 = t >> 2;          // atom 0..63
    const int cg = (t & 3) * 4;     // ch2 base: 0,4,8,12
    float acc2[4] = {0.f, 0.f, 0.f, 0.f};
    #pragma unroll
    for (int k = 0; k < 64; k += 4) {
        const float4 x4 = *reinterpret_cast<const float4*>(&h1[a2][k]);
        #pragma unroll
        for (int c = 0; c < 4; ++c) {
            const float4 w4 = *reinterpret_cast<const float4*>(&W2f[(cg + c) * 64 + k]);
            acc2[c] = fmaf(x4.x, w4.x, acc2[c]);
            acc2[c] = fmaf(x4.y, w4.y, acc2[c]);
            acc2[c] = fmaf(x4.z, w4.z, acc2[c]);
            acc2[c] = fmaf(x4.w, w4.w, acc2[c]);
        }
    }
    #pragma unroll
    for (int c = 0; c < 4; ++c) {
        float v = acc2[c] + b2f[cg + c];
        v = v / (1.0f + __expf(-v));
        h2[a2][cg + c] = v;
    }
    __syncthreads();

    // Layer 3: [64 x 16] @ W3f^T -> [64]; f_u = exp(y)*0.1, broadcast x3
    if (t < TA) {
        float y = b3f[0];
        #pragma unroll
        for (int j = 0; j < 16; ++j)
            y = fmaf(h2[t][j], W3f[j], y);
        const float fu = __expf(y) * 0.1f;
        float* o = out + OUT_FUNC + 3 * (abase + t);
        o[0] = fu; o[1] = fu; o[2] = fu;
    }
}

extern "C" void kernel_launch(void* const* d_in, const int* in_sizes, int n_in,
                              void* d_out, int out_size, void* d_ws, size_t ws_size,
                              hipStream_t stream) {
    const float* nf     = (const float*)d_in[0];
    const float* energy = (const float*)d_in[1];
    const float* forces = (const float*)d_in[2];
    const float* stress = (const float*)d_in[3];
    const float* W1f    = (const float*)d_in[10];
    const float* b1f    = (const float*)d_in[11];
    const float* W2f    = (const float*)d_in[12];
    const float* b2f    = (const float*)d_in[13];
    const float* W3f    = (const float*)d_in[14];
    const float* b3f    = (const float*)d_in[15];
    float* out = (float*)d_out;

    dim3 grid(N_ATOMS / TA);   // 800 blocks
    funcert_kernel<<<grid, BLK, 0, stream>>>(nf, energy, forces, stress,
                                             W1f, b1f, W2f, b2f, W3f, b3f, out);
}

// Round 2
// 132.340 us; speedup vs baseline: 1.3265x; 1.3265x over previous
//
#include <hip/hip_runtime.h>
#include <hip/hip_bf16.h>

#define N_ATOMS 51200
#define N_MOL   512
#define FEAT    384

// Output layout (flat, reference return order):
//   energy[512]@0, forces[153600]@512, stress[4608]@154112,
//   energy_uncert[512]@158720 (=0.6), force_uncert[153600]@159232 (computed),
//   stress_uncert[4608]@312832 (=0.1/16)
#define OUT_FUNC   159232
#define COPY_TOTAL 163840

constexpr int TA  = 64;
constexpr int BLK = 256;

__global__ __launch_bounds__(BLK) void funcert_kernel(
    const float* __restrict__ nf,
    const float* __restrict__ energy,
    const float* __restrict__ forces,
    const float* __restrict__ stress,
    const float* __restrict__ W1f, const float* __restrict__ b1f,
    const float* __restrict__ W2f, const float* __restrict__ b2f,
    const float* __restrict__ W3f, const float* __restrict__ b3f,
    float* __restrict__ out)
{
    const int t   = threadIdx.x;
    const int gid = blockIdx.x * BLK + t;

    // ---- passthrough / constant outputs (verified exact in R1) ----
    if (gid < COPY_TOTAL) {
        float v; int o = gid;
        if      (gid < 512)    { v = energy[gid]; }
        else if (gid < 154112) { v = forces[gid - 512]; }
        else if (gid < 158720) { v = stress[gid - 154112]; }
        else if (gid < 159232) { v = 0.6f; }
        else                   { v = 0.1f / 16.0f; o = gid + 153600; }
        out[o] = v;
    }

    // ---- LDS: one 32 KB buffer, reused (X half-tile -> L2 partials + h2) ----
    __shared__ float4 smem4[64 * 32];          // 32768 B -> 5 blocks/CU
    float* smem = (float*)smem4;

    const int lane  = t & 63;                             // lane == atom
    const int w     = __builtin_amdgcn_readfirstlane(t >> 6);  // wave id, uniform
    const int abase = blockIdx.x * TA;
    const float4* nf4 = (const float4*)nf;                // row stride 96 float4

    float acc[16];
    #pragma unroll
    for (int j = 0; j < 16; ++j) acc[j] = 0.0f;

    const float* Wr = W1f + w * 16 * 256;     // this wave's 16 rows of W1f

    // Swizzled read-address helpers: byte = lane*512 + (k4&24)*16 + ((k4^lane)&7)*16
    const int Abase = lane * 512;
    int Bx[8];
    #pragma unroll
    for (int e = 0; e < 8; ++e) Bx[e] = (((lane & 7) ^ e) * 16);

    #pragma unroll 1
    for (int h = 0; h < 2; ++h) {
        // -- stage K-half h: 64 rows x 32 float4, XOR-swizzle on SOURCE, LDS linear --
        #pragma unroll
        for (int i = 0; i < 8; ++i) {
            const int slot_base = i * 256 + w * 64;       // wave-uniform LDS base
            const int s   = slot_base + lane;
            const int row = s >> 5;
            const int f   = s & 31;
            const int k4  = (f & 24) | ((f ^ row) & 7);   // involution of low 3 bits
            const int g4  = h ? (64 + k4) : k4;           // concat: f4 0..31 | 64..95
            const float4* src = nf4 + (size_t)(abase + row) * 96 + g4;
            __builtin_amdgcn_global_load_lds(
                (const __attribute__((address_space(1))) void*)src,
                (__attribute__((address_space(3))) void*)(smem4 + slot_base),
                16, 0, 0);
        }
        __syncthreads();

        // -- L1 compute over this K-half: lane=atom, 16 channels, W via s_load --
        const float* Wh = Wr + h * 128;
        #pragma unroll 2
        for (int kb = 0; kb < 4; ++kb) {
            #pragma unroll
            for (int u = 0; u < 8; ++u) {
                const float4 x4 = *(const float4*)((const char*)smem +
                                                   (Abase + kb * 128 + Bx[u]));
                const int ko = kb * 32 + u * 4;
                #pragma unroll
                for (int j = 0; j < 16; ++j) {
                    const float* wp = Wh + j * 256 + ko;  // wave-uniform -> s_load
                    acc[j] = fmaf(x4.x, wp[0], acc[j]);
                    acc[j] = fmaf(x4.y, wp[1], acc[j]);
                    acc[j] = fmaf(x4.z, wp[2], acc[j]);
                    acc[j] = fmaf(x4.w, wp[3], acc[j]);
                }
            }
        }
        __syncthreads();   // all waves done reading this half before overwrite/reuse
    }

    // ---- bias + silu (in place) ----
    #pragma unroll
    for (int j = 0; j < 16; ++j) {
        const float v = acc[j] + b1f[w * 16 + j];
        acc[j] = v * __builtin_amdgcn_rcpf(1.0f + __expf(-v));
    }

    // ---- L2 partials: p[c2] = sum_j h1[j] * W2f[c2][16w+j]; write to LDS ----
    #pragma unroll
    for (int c2 = 0; c2 < 16; ++c2) {
        float s = 0.0f;
        #pragma unroll
        for (int j = 0; j < 16; ++j)
            s = fmaf(acc[j], W2f[c2 * 64 + w * 16 + j], s);
        smem[c2 * 256 + w * 64 + lane] = s;   // [16][4 waves][64 atoms]
    }
    __syncthreads();

    // ---- reduce across waves + bias + silu -> h2 ----
    float* h2b = smem + 4096;                 // [64][17] floats, after partials
    #pragma unroll
    for (int i = 0; i < 4; ++i) {
        const int c2 = i * 4 + w;             // uniform per wave
        float s = smem[c2 * 256 +       lane] + smem[c2 * 256 +  64 + lane]
                + smem[c2 * 256 + 128 + lane] + smem[c2 * 256 + 192 + lane];
        s += b2f[c2];
        h2b[lane * 17 + c2] = s * __builtin_amdgcn_rcpf(1.0f + __expf(-s));
    }
    __syncthreads();

    // ---- L3 + exp: one lane per atom ----
    if (t < TA) {
        float y = b3f[0];
        #pragma unroll
        for (int j = 0; j < 16; ++j)
            y = fmaf(h2b[t * 17 + j], W3f[j], y);
        const float fu = __expf(y) * 0.1f;
        float* o = out + OUT_FUNC + 3 * (abase + t);
        o[0] = fu; o[1] = fu; o[2] = fu;
    }
}

extern "C" void kernel_launch(void* const* d_in, const int* in_sizes, int n_in,
                              void* d_out, int out_size, void* d_ws, size_t ws_size,
                              hipStream_t stream) {
    const float* nf     = (const float*)d_in[0];
    const float* energy = (const float*)d_in[1];
    const float* forces = (const float*)d_in[2];
    const float* stress = (const float*)d_in[3];
    const float* W1f    = (const float*)d_in[10];
    const float* b1f    = (const float*)d_in[11];
    const float* W2f    = (const float*)d_in[12];
    const float* b2f    = (const float*)d_in[13];
    const float* W3f    = (const float*)d_in[14];
    const float* b3f    = (const float*)d_in[15];
    float* out = (float*)d_out;

    dim3 grid(N_ATOMS / TA);   // 800 blocks
    funcert_kernel<<<grid, BLK, 0, stream>>>(nf, energy, forces, stress,
                                             W1f, b1f, W2f, b2f, W3f, b3f, out);
}

// Round 3
// 23.917 us; speedup vs baseline: 7.3398x; 5.5333x over previous
//
#include <hip/hip_runtime.h>
#include <hip/hip_bf16.h>

#define N_ATOMS 51200
#define FEAT    384

// Output layout (flat, reference return order):
//   energy[512]@0, forces[153600]@512, stress[4608]@154112,
//   energy_uncert[512]@158720 (=0.6), force_uncert[153600]@159232 (computed),
//   stress_uncert[4608]@312832 (=0.1/16)
#define OUT_FUNC   159232
#define COPY_TOTAL 163840

typedef __attribute__((ext_vector_type(4))) float f32x4;
typedef __attribute__((ext_vector_type(4))) short s16x4;
typedef __attribute__((ext_vector_type(8))) short s16x8;   // 8 bf16 = 4 VGPRs (MFMA A/B frag)

constexpr int BLK = 256;

__device__ __forceinline__ short f2bf(float x) {
    union { __hip_bfloat16 b; short s; } u;
    u.b = __float2bfloat16(x);            // RNE
    return u.s;
}
__device__ __forceinline__ float silu_(float v) {
    return v / (1.0f + __expf(-v));
}

__global__ __launch_bounds__(BLK) void funcert_kernel(
    const float* __restrict__ nf,
    const float* __restrict__ energy,
    const float* __restrict__ forces,
    const float* __restrict__ stress,
    const float* __restrict__ W1f, const float* __restrict__ b1f,
    const float* __restrict__ W2f, const float* __restrict__ b2f,
    const float* __restrict__ W3f, const float* __restrict__ b3f,
    float* __restrict__ out)
{
    const int t   = threadIdx.x;
    const int gid = blockIdx.x * BLK + t;

    // ---- passthrough / constant outputs (exact, verified R1/R2) ----
    if (gid < COPY_TOTAL) {
        float v; int o = gid;
        if      (gid < 512)    { v = energy[gid]; }
        else if (gid < 154112) { v = forces[gid - 512]; }
        else if (gid < 158720) { v = stress[gid - 154112]; }
        else if (gid < 159232) { v = 0.6f; }
        else                   { v = 0.1f / 16.0f; o = gid + 153600; }
        out[o] = v;
    }

    __shared__ short Xs[64 * 256];   // 32 KB: X tile bf16, rows=atom (512B), 16B slots XOR-swizzled
    __shared__ short H1s[64 * 64];   // 8 KB: h1 bf16, rows=atom (128B)

    const int lane  = t & 63;
    const int w     = t >> 6;        // wave id: ch-slice for L1, atom-tile for L2
    const int g     = lane >> 4;     // k-subgroup
    const int col   = lane & 15;     // MFMA col index (B n / D n); also A row
    const int abase = blockIdx.x * 64;

    // ---- W1f B-fragments: ch = 16w+col, k = ks*32 + g*8 + j (same mapping as A) ----
    const int ch = w * 16 + col;
    s16x8 wfrag[8];
    #pragma unroll
    for (int ks = 0; ks < 8; ++ks) {
        const float* p = W1f + ch * 256 + ks * 32 + g * 8;
        const f32x4 lo = *(const f32x4*)p;
        const f32x4 hi = *(const f32x4*)(p + 4);
        s16x8 f;
        f[0]=f2bf(lo.x); f[1]=f2bf(lo.y); f[2]=f2bf(lo.z); f[3]=f2bf(lo.w);
        f[4]=f2bf(hi.x); f[5]=f2bf(hi.y); f[6]=f2bf(hi.z); f[7]=f2bf(hi.w);
        wfrag[ks] = f;
    }
    const float b1v = b1f[ch];

    // ---- stage X tile: f32 coalesced -> cvt bf16 -> LDS (swizzled 16B slots) ----
    // wave w stages rows i*4+w; lane = logical f4-column (concat handled in g4)
    #pragma unroll
    for (int i = 0; i < 16; ++i) {
        const int r  = i * 4 + w;
        const int g4 = lane + (lane >= 32 ? 32 : 0);   // concat: [0:128) U [256:384)
        const f32x4 x = ((const f32x4*)nf)[(size_t)(abase + r) * 96 + g4];
        const int sp = (lane >> 1) ^ (r & 7);          // 16B-slot XOR swizzle
        s16x4 b; b.x=f2bf(x.x); b.y=f2bf(x.y); b.z=f2bf(x.z); b.w=f2bf(x.w);
        *(s16x4*)(Xs + r * 256 + sp * 8 + (lane & 1) * 4) = b;
    }
    __syncthreads();

    // ---- L1: per wave, 4 M-tiles x 8 k-steps, 16x16x32 bf16 MFMA ----
    #pragma unroll
    for (int mt = 0; mt < 4; ++mt) {
        const int row = mt * 16 + col;                 // A row = atom
        f32x4 a = {0.f, 0.f, 0.f, 0.f};
        #pragma unroll
        for (int ks = 0; ks < 8; ++ks) {
            const int sp = (ks * 4 + g) ^ (row & 7);
            const s16x8 af = *(const s16x8*)(Xs + row * 256 + sp * 8);
            a = __builtin_amdgcn_mfma_f32_16x16x32_bf16(af, wfrag[ks], a, 0, 0, 0);
        }
        // D: lane holds ch=16w+col, atoms mt*16 + g*4 + r
        #pragma unroll
        for (int r = 0; r < 4; ++r) {
            const int atom = mt * 16 + g * 4 + r;
            H1s[atom * 64 + ch] = f2bf(silu_(a[r] + b1v));
        }
    }
    __syncthreads();

    // ---- L2: wave w -> atoms [16w,16w+16), 2 k-steps over 64 ch ----
    s16x8 w2frag[2];
    #pragma unroll
    for (int ks = 0; ks < 2; ++ks) {
        const float* p = W2f + col * 64 + ks * 32 + g * 8;   // B2[k][n]=W2f[n][k]
        const f32x4 lo = *(const f32x4*)p;
        const f32x4 hi = *(const f32x4*)(p + 4);
        s16x8 f;
        f[0]=f2bf(lo.x); f[1]=f2bf(lo.y); f[2]=f2bf(lo.z); f[3]=f2bf(lo.w);
        f[4]=f2bf(hi.x); f[5]=f2bf(hi.y); f[6]=f2bf(hi.z); f[7]=f2bf(hi.w);
        w2frag[ks] = f;
    }
    const int arow = w * 16 + col;                     // atom for A2
    f32x4 a2 = {0.f, 0.f, 0.f, 0.f};
    #pragma unroll
    for (int ks = 0; ks < 2; ++ks) {
        const s16x8 af = *(const s16x8*)(H1s + arow * 64 + ks * 32 + g * 8);
        a2 = __builtin_amdgcn_mfma_f32_16x16x32_bf16(af, w2frag[ks], a2, 0, 0, 0);
    }

    // ---- h2 + L3 + exp: lane owns ch2=col for atoms 16w + g*4 + r ----
    const float b2v = b2f[col];
    const float w3v = W3f[col];
    float y[4];
    #pragma unroll
    for (int r = 0; r < 4; ++r)
        y[r] = silu_(a2[r] + b2v) * w3v;
    #pragma unroll
    for (int m = 1; m < 16; m <<= 1) {
        #pragma unroll
        for (int r = 0; r < 4; ++r)
            y[r] += __shfl_xor(y[r], m, 64);           // reduce over 16 cols
    }
    const float b3v = b3f[0];
    float fu[4];
    #pragma unroll
    for (int r = 0; r < 4; ++r)
        fu[r] = __expf(y[r] + b3v) * 0.1f;

    if (col < 12) {                                    // 4 atoms x 3 comps per 16-lane group
        const int a_ = col / 3, c = col - a_ * 3;
        const float v = (a_ == 0) ? fu[0] : (a_ == 1) ? fu[1] : (a_ == 2) ? fu[2] : fu[3];
        const int atom = w * 16 + g * 4 + a_;
        out[OUT_FUNC + 3 * (abase + atom) + c] = v;
    }
}

extern "C" void kernel_launch(void* const* d_in, const int* in_sizes, int n_in,
                              void* d_out, int out_size, void* d_ws, size_t ws_size,
                              hipStream_t stream) {
    const float* nf     = (const float*)d_in[0];
    const float* energy = (const float*)d_in[1];
    const float* forces = (const float*)d_in[2];
    const float* stress = (const float*)d_in[3];
    const float* W1f    = (const float*)d_in[10];
    const float* b1f    = (const float*)d_in[11];
    const float* W2f    = (const float*)d_in[12];
    const float* b2f    = (const float*)d_in[13];
    const float* W3f    = (const float*)d_in[14];
    const float* b3f    = (const float*)d_in[15];
    float* out = (float*)d_out;

    dim3 grid(N_ATOMS / 64);   // 800 blocks
    funcert_kernel<<<grid, BLK, 0, stream>>>(nf, energy, forces, stress,
                                             W1f, b1f, W2f, b2f, W3f, b3f, out);
}